// Round 9
// baseline (316.411 us; speedup 1.0000x reference)
//
#include <hip/hip_runtime.h>
#include <hip/hip_cooperative_groups.h>
#include <cstdint>

// B,D,H,W,C = 4,8,16,16,512; R=64; F=256; rows=8192; keys/batch=2048.
// v10: v9 bodies (champion: barrier-free reg-direct B, 1-deep prefetch,
//   T14 early x-loads, T5 setprio) FUSED into ONE cooperative kernel:
//   part0 (weight pack, 64 blocks) -> grid.sync -> part1 (QKV GEMM) ->
//   grid.sync -> part2 (attn+LN+MLP+LN). Deletes 2 dispatch boundaries.
//   Cross-XCD visibility across grid.sync: __threadfence (device scope)
//   + cooperative grid barrier (device-scope atomics), per Guideline 16.
namespace cg = cooperative_groups;
#define LN_EPS 1e-3f
using u16 = unsigned short;
using u32 = unsigned int;
typedef __attribute__((ext_vector_type(8))) short bh8;   // 8 bf16
typedef __attribute__((ext_vector_type(4))) float f4;    // 4 f32 acc
#define MFMA16(A,B,C) __builtin_amdgcn_mfma_f32_16x16x32_bf16((A),(B),(C),0,0,0)
#define LKBAR() do{ asm volatile("s_waitcnt lgkmcnt(0)" ::: "memory"); \
                    __builtin_amdgcn_s_barrier(); asm volatile("" ::: "memory"); }while(0)

__device__ __forceinline__ u16 bf16r(float f){
    union{float f;u32 u;} c; c.f=f;
    return (u16)((c.u + 0x7fffu + ((c.u>>16)&1u))>>16);
}
__device__ __forceinline__ u32 pk2(float a, float b){
    return (u32)bf16r(a) | ((u32)bf16r(b)<<16);
}

__global__ __launch_bounds__(512) void fused_all(
    const float* __restrict__ x,
    const float* __restrict__ wq, const float* __restrict__ bq,
    const float* __restrict__ wk, const float* __restrict__ bk,
    const float* __restrict__ wv, const float* __restrict__ bv,
    const float* __restrict__ wm, const float* __restrict__ bm,
    const float* __restrict__ g1, const float* __restrict__ b1,
    const float* __restrict__ g2, const float* __restrict__ b2,
    u16* __restrict__ wqkv_p, u16* __restrict__ wm_p,
    u16* __restrict__ Qb, u16* __restrict__ Kb, u16* __restrict__ Vb,
    float* __restrict__ out)
{
    __shared__ u16 Asf[16384];      // part1: A frags (32 KB)
    __shared__ u16 U[16384];        // part2: a2f/y1f union (32 KB)
    __shared__ float redA[256], redB[256];
    cg::grid_group grid = cg::this_grid();
    const int t = threadIdx.x, w = t>>6, lane = t&63, quad = (lane>>4)&3, c = lane&15;

    // ================= Part 0: pack weights (blocks 0..63, threads 0..255) ====
    if (blockIdx.x < 64 && t < 256){
        const int c0 = t & 15, qn = t >> 4;
        const int q0 = qn & 3, ntl = qn >> 2;
        const int blk = blockIdx.x;
        if (blk < 32){
            const int s = blk >> 1, hh = blk & 1;
            const int krow = s*32 + q0*8;
            u16* dst = wqkv_p + (size_t)s*20480;
            #pragma unroll
            for (int i=0;i<5;++i){
                const int nt = hh*20 + i*4 + ntl;
                const int n = nt*16 + c0;
                const float* src; int ldw;
                if (n < 64){ src = wq + (size_t)krow*64 + n; ldw = 64; }
                else if (n < 128){ src = wk + (size_t)krow*64 + (n-64); ldw = 64; }
                else { src = wv + (size_t)krow*512 + (n-128); ldw = 512; }
                float v[8];
                #pragma unroll
                for (int j=0;j<8;++j) v[j] = src[(size_t)j*ldw];
                uint4 o; o.x=pk2(v[0],v[1]); o.y=pk2(v[2],v[3]); o.z=pk2(v[4],v[5]); o.w=pk2(v[6],v[7]);
                *(uint4*)&dst[((nt*4+q0)*16 + c0)*8] = o;
            }
        } else {
            const int bb = blk - 32;
            const int s = bb >> 1, hh = bb & 1;
            const int krow = s*32 + q0*8;
            u16* dst = wm_p + (size_t)s*16384;
            #pragma unroll
            for (int i=0;i<4;++i){
                const int nt = hh*16 + i*4 + ntl;
                const int n = nt*16 + c0;
                const float* src = wm + (size_t)krow*512 + n;
                float v[8];
                #pragma unroll
                for (int j=0;j<8;++j) v[j] = src[(size_t)j*512];
                uint4 o; o.x=pk2(v[0],v[1]); o.y=pk2(v[2],v[3]); o.z=pk2(v[4],v[5]); o.w=pk2(v[6],v[7]);
                *(uint4*)&dst[((nt*4+q0)*16 + c0)*8] = o;
            }
        }
    }
    __threadfence();
    grid.sync();

    // ================= Part 1: fused QKV projection ===========================
    {
        const int rowbase = blockIdx.x << 5;
        // prefetch B s=0 (overlaps A-stage)
        bh8 bw[5];
        #pragma unroll
        for (int nt2=0;nt2<5;++nt2)
            bw[nt2] = *(const bh8*)&wqkv_p[(size_t)((w*5+nt2)*4 + quad)*128 + c*8];
        // stage A (32 rows x 512 f32 -> bf16 frag order), coalesced float4
        #pragma unroll
        for (int i=0;i<8;++i){
            const int idx = t + (i<<9);
            const int fr = idx >> 7, fc4 = idx & 127;
            float4 xv = *(const float4*)&x[(size_t)(rowbase+fr)*512 + fc4*4];
            uint2 pkv; pkv.x = pk2(xv.x,xv.y); pkv.y = pk2(xv.z,xv.w);
            const int s = fc4 >> 3, qd = (fc4 >> 1) & 3, j0 = (fc4 & 1)*4;
            *(uint2*)&Asf[(fr>>4)*8192 + s*512 + (qd*16 + (fr&15))*8 + j0] = pkv;
        }
        f4 acc[2][5];
        #pragma unroll
        for (int rt=0;rt<2;++rt)
            #pragma unroll
            for (int i=0;i<5;++i) acc[rt][i] = (f4){0.f,0.f,0.f,0.f};
        __syncthreads();

        #pragma unroll
        for (int s=0;s<16;++s){
            bh8 bn[5];
            if (s+1 < 16){
                #pragma unroll
                for (int nt2=0;nt2<5;++nt2)
                    bn[nt2] = *(const bh8*)&wqkv_p[(size_t)(s+1)*20480 + ((w*5+nt2)*4 + quad)*128 + c*8];
            }
            bh8 a[2];
            #pragma unroll
            for (int rt=0;rt<2;++rt)
                a[rt] = *(const bh8*)&Asf[rt*8192 + s*512 + (quad*16+c)*8];
            __builtin_amdgcn_s_setprio(1);
            #pragma unroll
            for (int rt=0;rt<2;++rt)
                #pragma unroll
                for (int nt2=0;nt2<5;++nt2)
                    acc[rt][nt2] = MFMA16(a[rt], bw[nt2], acc[rt][nt2]);
            __builtin_amdgcn_s_setprio(0);
            if (s+1 < 16){
                #pragma unroll
                for (int nt2=0;nt2<5;++nt2) bw[nt2] = bn[nt2];
            }
        }

        // epilogue: Q/K -> frag panels (+bias); V -> B-operand frag layout
        const int bd = rowbase >> 8;
        #pragma unroll
        for (int rt=0;rt<2;++rt){
            const int rtg = (blockIdx.x<<1) + rt;
            const int kloc = (rowbase & 255) + rt*16 + quad*4;
            const int sv = kloc >> 5, kq = (kloc >> 3) & 3, jk0 = kloc & 7;
            #pragma unroll
            for (int nt2=0;nt2<5;++nt2){
                const int colb = w*80 + nt2*16;
                if (colb < 128){
                    const bool isK = (colb >= 64);
                    const int r = colb - (isK ? 64 : 0) + c;
                    const float bias = isK ? bk[r] : bq[r];
                    u16* dstb = (isK ? Kb : Qb) + ((size_t)(rtg*2 + (r>>5))*4 + ((r>>3)&3))*128 + (r&7);
                    #pragma unroll
                    for (int reg=0;reg<4;++reg)
                        dstb[(quad*4+reg)*8] = bf16r(acc[rt][nt2][reg] + bias);
                } else {
                    const int ntv = (colb - 128) >> 4;
                    u16* dstv = Vb + (size_t)bd*131072 + (size_t)sv*16384
                                   + (size_t)((ntv*4+kq)*128 + c*8 + jk0);
                    ushort4 o;
                    o.x = bf16r(acc[rt][nt2][0]); o.y = bf16r(acc[rt][nt2][1]);
                    o.z = bf16r(acc[rt][nt2][2]); o.w = bf16r(acc[rt][nt2][3]);
                    *(ushort4*)dstv = o;
                }
            }
        }
    }
    __threadfence();
    grid.sync();

    // ================= Part 2: attn + LN + MLP + LN ===========================
    {
        const int bd = blockIdx.x & 31, ftile = blockIdx.x >> 5;
        const int b = bd >> 3;
        const int rowbase = (bd<<8) + (ftile<<5);
        const int rt00 = rowbase >> 4;
        const u16* Kp = Kb + (size_t)b*131072;
        const u16* Vp = Vb + (size_t)bd*131072;

        bh8 aq[2][2];
        #pragma unroll
        for (int rt=0;rt<2;++rt)
            #pragma unroll
            for (int kk=0;kk<2;++kk)
                aq[rt][kk] = *(const bh8*)&Qb[(size_t)(rt00+rt)*1024 + kk*512 + (quad*16+c)*8];

        float a2r[2][2][4] = {};
        bh8 bk0[2][2];
        #pragma unroll
        for (int kt=0;kt<2;++kt)
            #pragma unroll
            for (int kk=0;kk<2;++kk)
                bk0[kt][kk] = *(const bh8*)&Kp[(size_t)(w*2+kt)*1024 + kk*512 + (quad*16+c)*8];
        #pragma unroll
        for (int cc=0; cc<8; ++cc){
            bh8 bn[2][2];
            if (cc+1 < 8){
                #pragma unroll
                for (int kt=0;kt<2;++kt)
                    #pragma unroll
                    for (int kk=0;kk<2;++kk)
                        bn[kt][kk] = *(const bh8*)&Kp[(size_t)((cc+1)*16 + w*2+kt)*1024 + kk*512 + (quad*16+c)*8];
            }
            f4 sa[2][2];
            __builtin_amdgcn_s_setprio(1);
            #pragma unroll
            for (int rt=0;rt<2;++rt)
                #pragma unroll
                for (int kt=0;kt<2;++kt){
                    sa[rt][kt] = (f4){0.f,0.f,0.f,0.f};
                    sa[rt][kt] = MFMA16(aq[rt][0], bk0[kt][0], sa[rt][kt]);
                    sa[rt][kt] = MFMA16(aq[rt][1], bk0[kt][1], sa[rt][kt]);
                }
            __builtin_amdgcn_s_setprio(0);
            #pragma unroll
            for (int rt=0;rt<2;++rt)
                #pragma unroll
                for (int kt=0;kt<2;++kt)
                    #pragma unroll
                    for (int reg=0;reg<4;++reg)
                        a2r[rt][kt][reg] += __expf(sa[rt][kt][reg]);
            if (cc+1 < 8){
                #pragma unroll
                for (int kt=0;kt<2;++kt)
                    #pragma unroll
                    for (int kk=0;kk<2;++kk) bk0[kt][kk] = bn[kt][kk];
            }
        }
        // prefetch V s=0
        bh8 bv8[4];
        #pragma unroll
        for (int nt2=0;nt2<4;++nt2)
            bv8[nt2] = *(const bh8*)&Vp[(size_t)((w*4+nt2)*4 + quad)*128 + c*8];
        // softmax denominator
        float lp[2][4];
        #pragma unroll
        for (int rt=0;rt<2;++rt)
            #pragma unroll
            for (int reg=0;reg<4;++reg){
                float v = a2r[rt][0][reg] + a2r[rt][1][reg];
                v += __shfl_xor(v,1,64); v += __shfl_xor(v,2,64);
                v += __shfl_xor(v,4,64); v += __shfl_xor(v,8,64);
                lp[rt][reg] = v;
            }
        if (c==0){
            #pragma unroll
            for (int rt=0;rt<2;++rt)
                #pragma unroll
                for (int reg=0;reg<4;++reg) redA[w*32 + rt*16 + quad*4+reg] = lp[rt][reg];
        }
        LKBAR();
        float fac[2][4];
        #pragma unroll
        for (int rt=0;rt<2;++rt)
            #pragma unroll
            for (int reg=0;reg<4;++reg){
                const int q = rt*16 + quad*4 + reg;
                float s = 0.f;
                #pragma unroll
                for (int ww=0;ww<8;++ww) s += redA[ww*32 + q];
                fac[rt][reg] = 1.f/s;
            }
        #pragma unroll
        for (int rt=0;rt<2;++rt)
            #pragma unroll
            for (int kt=0;kt<2;++kt)
                #pragma unroll
                for (int reg=0;reg<4;++reg){
                    const int jp = w*32 + kt*16 + c;
                    U[rt*4096 + (jp>>5)*512 + (((jp>>3)&3)*16 + quad*4+reg)*8 + (jp&7)]
                        = bf16r(a2r[rt][kt][reg]*fac[rt][reg]);
                }
        LKBAR();                    // a2f visible; V prefetch (regs) untouched

        // early-issue x-residual loads (T14)
        float xr[2][4][4];
        #pragma unroll
        for (int rt=0;rt<2;++rt)
            #pragma unroll
            for (int nt2=0;nt2<4;++nt2){
                const int col = w*64 + nt2*16 + c;
                #pragma unroll
                for (int reg=0;reg<4;++reg){
                    const int row = rowbase + rt*16 + quad*4 + reg;
                    xr[rt][nt2][reg] = x[(size_t)row*512 + col];
                }
            }

        // Phase B: attn = a2 @ V
        f4 cacc[2][4];
        #pragma unroll
        for (int rt=0;rt<2;++rt)
            #pragma unroll
            for (int i=0;i<4;++i) cacc[rt][i] = (f4){0.f,0.f,0.f,0.f};
        #pragma unroll
        for (int s8=0;s8<8;++s8){
            bh8 bn[4];
            if (s8+1 < 8){
                #pragma unroll
                for (int nt2=0;nt2<4;++nt2)
                    bn[nt2] = *(const bh8*)&Vp[(size_t)(s8+1)*16384 + ((w*4+nt2)*4 + quad)*128 + c*8];
            }
            bh8 a[2];
            #pragma unroll
            for (int rt=0;rt<2;++rt)
                a[rt] = *(const bh8*)&U[rt*4096 + s8*512 + (quad*16+c)*8];
            __builtin_amdgcn_s_setprio(1);
            #pragma unroll
            for (int rt=0;rt<2;++rt)
                #pragma unroll
                for (int nt2=0;nt2<4;++nt2)
                    cacc[rt][nt2] = MFMA16(a[rt], bv8[nt2], cacc[rt][nt2]);
            __builtin_amdgcn_s_setprio(0);
            if (s8+1 < 8){
                #pragma unroll
                for (int nt2=0;nt2<4;++nt2) bv8[nt2] = bn[nt2];
            }
        }
        // prefetch wm s=0
        bh8 bm8[4];
        #pragma unroll
        for (int nt2=0;nt2<4;++nt2)
            bm8[nt2] = *(const bh8*)&wm_p[(size_t)((w*4+nt2)*4 + quad)*128 + c*8];

        // epilogue 1: + bv + x residual, LN -> y1
        float mean1[2][4], rstd1[2][4];
        {
            float sv4[2][4] = {}, qv2[2][4] = {};
            #pragma unroll
            for (int rt=0;rt<2;++rt)
                #pragma unroll
                for (int nt2=0;nt2<4;++nt2){
                    const int col = w*64 + nt2*16 + c;
                    const float bvv = bv[col];
                    #pragma unroll
                    for (int reg=0;reg<4;++reg){
                        float val = cacc[rt][nt2][reg] + bvv + xr[rt][nt2][reg];
                        cacc[rt][nt2][reg] = val;
                        sv4[rt][reg] += val; qv2[rt][reg] = fmaf(val,val,qv2[rt][reg]);
                    }
                }
            #pragma unroll
            for (int rt=0;rt<2;++rt)
                #pragma unroll
                for (int reg=0;reg<4;++reg){
                    float s1=sv4[rt][reg], s2=qv2[rt][reg];
                    s1 += __shfl_xor(s1,1,64); s2 += __shfl_xor(s2,1,64);
                    s1 += __shfl_xor(s1,2,64); s2 += __shfl_xor(s2,2,64);
                    s1 += __shfl_xor(s1,4,64); s2 += __shfl_xor(s2,4,64);
                    s1 += __shfl_xor(s1,8,64); s2 += __shfl_xor(s2,8,64);
                    sv4[rt][reg]=s1; qv2[rt][reg]=s2;
                }
            if (c==0){
                #pragma unroll
                for (int rt=0;rt<2;++rt)
                    #pragma unroll
                    for (int reg=0;reg<4;++reg){
                        redA[w*32 + rt*16 + quad*4+reg]=sv4[rt][reg];
                        redB[w*32 + rt*16 + quad*4+reg]=qv2[rt][reg];
                    }
            }
            LKBAR();
            #pragma unroll
            for (int rt=0;rt<2;++rt)
                #pragma unroll
                for (int reg=0;reg<4;++reg){
                    const int q = rt*16 + quad*4 + reg;
                    float S=0.f, Q2=0.f;
                    #pragma unroll
                    for (int ww=0;ww<8;++ww){ S += redA[ww*32+q]; Q2 += redB[ww*32+q]; }
                    const float m = S*(1.f/512.f);
                    mean1[rt][reg]=m; rstd1[rt][reg]=rsqrtf(Q2*(1.f/512.f) - m*m + LN_EPS);
                }
            #pragma unroll
            for (int rt=0;rt<2;++rt)
                #pragma unroll
                for (int nt2=0;nt2<4;++nt2){
                    const int col = w*64 + nt2*16 + c;
                    const float gg = g1[col], bb1 = b1[col];
                    #pragma unroll
                    for (int reg=0;reg<4;++reg){
                        float y = (cacc[rt][nt2][reg]-mean1[rt][reg])*rstd1[rt][reg]*gg + bb1;
                        cacc[rt][nt2][reg] = y;
                        U[rt*8192 + (col>>5)*512 + (((col>>3)&3)*16 + quad*4+reg)*8 + (col&7)] = bf16r(y);
                    }
                }
            LKBAR();
        }

        // Phase D: mlp = y1 @ wm
        f4 dacc[2][4];
        #pragma unroll
        for (int rt=0;rt<2;++rt)
            #pragma unroll
            for (int i=0;i<4;++i) dacc[rt][i] = (f4){0.f,0.f,0.f,0.f};
        #pragma unroll
        for (int s=0;s<16;++s){
            bh8 bn[4];
            if (s+1 < 16){
                #pragma unroll
                for (int nt2=0;nt2<4;++nt2)
                    bn[nt2] = *(const bh8*)&wm_p[(size_t)(s+1)*16384 + ((w*4+nt2)*4 + quad)*128 + c*8];
            }
            bh8 a[2];
            #pragma unroll
            for (int rt=0;rt<2;++rt)
                a[rt] = *(const bh8*)&U[rt*8192 + s*512 + (quad*16+c)*8];
            __builtin_amdgcn_s_setprio(1);
            #pragma unroll
            for (int rt=0;rt<2;++rt)
                #pragma unroll
                for (int nt2=0;nt2<4;++nt2)
                    dacc[rt][nt2] = MFMA16(a[rt], bm8[nt2], dacc[rt][nt2]);
            __builtin_amdgcn_s_setprio(0);
            if (s+1 < 16){
                #pragma unroll
                for (int nt2=0;nt2<4;++nt2) bm8[nt2] = bn[nt2];
            }
        }

        // epilogue 2: relu(+bm) + y1 residual, LN -> out
        {
            float sv4[2][4] = {}, qv2[2][4] = {};
            #pragma unroll
            for (int rt=0;rt<2;++rt)
                #pragma unroll
                for (int nt2=0;nt2<4;++nt2){
                    const int col = w*64 + nt2*16 + c;
                    const float bmv = bm[col];
                    #pragma unroll
                    for (int reg=0;reg<4;++reg){
                        float hh = fmaxf(dacc[rt][nt2][reg]+bmv, 0.f) + cacc[rt][nt2][reg];
                        dacc[rt][nt2][reg] = hh;
                        sv4[rt][reg] += hh; qv2[rt][reg] = fmaf(hh,hh,qv2[rt][reg]);
                    }
                }
            #pragma unroll
            for (int rt=0;rt<2;++rt)
                #pragma unroll
                for (int reg=0;reg<4;++reg){
                    float s1=sv4[rt][reg], s2=qv2[rt][reg];
                    s1 += __shfl_xor(s1,1,64); s2 += __shfl_xor(s2,1,64);
                    s1 += __shfl_xor(s1,2,64); s2 += __shfl_xor(s2,2,64);
                    s1 += __shfl_xor(s1,4,64); s2 += __shfl_xor(s2,4,64);
                    s1 += __shfl_xor(s1,8,64); s2 += __shfl_xor(s2,8,64);
                    sv4[rt][reg]=s1; qv2[rt][reg]=s2;
                }
            if (c==0){
                #pragma unroll
                for (int rt=0;rt<2;++rt)
                    #pragma unroll
                    for (int reg=0;reg<4;++reg){
                        redA[w*32 + rt*16 + quad*4+reg]=sv4[rt][reg];
                        redB[w*32 + rt*16 + quad*4+reg]=qv2[rt][reg];
                    }
            }
            LKBAR();
            #pragma unroll
            for (int rt=0;rt<2;++rt){
                float mean[4], rstd[4];
                #pragma unroll
                for (int reg=0;reg<4;++reg){
                    const int q = rt*16 + quad*4 + reg;
                    float S=0.f, Q2=0.f;
                    #pragma unroll
                    for (int ww=0;ww<8;++ww){ S += redA[ww*32+q]; Q2 += redB[ww*32+q]; }
                    const float m = S*(1.f/512.f);
                    mean[reg]=m; rstd[reg]=rsqrtf(Q2*(1.f/512.f) - m*m + LN_EPS);
                }
                #pragma unroll
                for (int nt2=0;nt2<4;++nt2){
                    const int col = w*64 + nt2*16 + c;
                    const float gg = g2[col], bb2 = b2[col];
                    #pragma unroll
                    for (int reg=0;reg<4;++reg){
                        const int row = rowbase + rt*16 + quad*4 + reg;
                        out[(size_t)row*512 + col] = (dacc[rt][nt2][reg]-mean[reg])*rstd[reg]*gg + bb2;
                    }
                }
            }
        }
    }
}

extern "C" void kernel_launch(void* const* d_in, const int* in_sizes, int n_in,
                              void* d_out, int out_size, void* d_ws, size_t ws_size,
                              hipStream_t stream) {
    (void)in_sizes; (void)n_in; (void)out_size; (void)ws_size;
    const float* x  = (const float*)d_in[0];
    const float* wq = (const float*)d_in[1];
    const float* bq = (const float*)d_in[2];
    const float* wk = (const float*)d_in[3];
    const float* bk = (const float*)d_in[4];
    const float* wv = (const float*)d_in[5];
    const float* bv = (const float*)d_in[6];
    const float* wm = (const float*)d_in[7];
    const float* bm = (const float*)d_in[8];
    const float* g1 = (const float*)d_in[9];
    const float* b1 = (const float*)d_in[10];
    const float* g2 = (const float*)d_in[11];
    const float* b2 = (const float*)d_in[12];

    // ws layout (11.67 MB): bf16 frag panels
    u16* wqkv_p = (u16*)d_ws;                  // 640 KB (16 s x 40 nt x 512)
    u16* wm_p   = wqkv_p + 327680;             // 512 KB
    u16* Qb     = wm_p   + 262144;             // 1 MB  (512 rt x 2048 B)
    u16* Kb     = Qb     + 524288;             // 1 MB
    u16* Vb     = Kb     + 524288;             // 8 MB  (32 bd x 8 s x 16384 u16)
    float* outp = (float*)d_out;

    void* args[] = { (void*)&x, (void*)&wq, (void*)&bq, (void*)&wk, (void*)&bk,
                     (void*)&wv, (void*)&bv, (void*)&wm, (void*)&bm,
                     (void*)&g1, (void*)&b1, (void*)&g2, (void*)&b2,
                     (void*)&wqkv_p, (void*)&wm_p,
                     (void*)&Qb, (void*)&Kb, (void*)&Vb, (void*)&outp };
    hipLaunchCooperativeKernel((const void*)fused_all, dim3(256), dim3(512),
                               args, 0, stream);
}

// Round 10
// 123.560 us; speedup vs baseline: 2.5608x; 2.5608x over previous
//
#include <hip/hip_runtime.h>
#include <cstdint>

// B,D,H,W,C = 4,8,16,16,512; R=64; F=256; rows=8192; keys/batch=2048.
// v11: v9 champion restored (barrier-free reg-direct B, 1-deep prefetch,
//   T14 early x-loads, T5 setprio) + one micro-lever: epilogue-1's bv/g1/b1
//   column vectors are early-issued alongside xr (same T14 pattern that won
//   in v9), hiding their latency under phase B's MFMA steps.
//   (v10 cooperative fusion reverted: VGPR 96 => full spill, 209us/dispatch.)
#define LN_EPS 1e-3f
using u16 = unsigned short;
using u32 = unsigned int;
typedef __attribute__((ext_vector_type(8))) short bh8;   // 8 bf16
typedef __attribute__((ext_vector_type(4))) float f4;    // 4 f32 acc
#define MFMA16(A,B,C) __builtin_amdgcn_mfma_f32_16x16x32_bf16((A),(B),(C),0,0,0)
#define LKBAR() do{ asm volatile("s_waitcnt lgkmcnt(0)" ::: "memory"); \
                    __builtin_amdgcn_s_barrier(); asm volatile("" ::: "memory"); }while(0)

__device__ __forceinline__ u16 bf16r(float f){
    union{float f;u32 u;} c; c.f=f;
    return (u16)((c.u + 0x7fffu + ((c.u>>16)&1u))>>16);
}
__device__ __forceinline__ u32 pk2(float a, float b){
    return (u32)bf16r(a) | ((u32)bf16r(b)<<16);
}

// ---------------- K0: pack weights -> bf16 frag-ordered B panels ----------------
__global__ __launch_bounds__(256) void k0_prep(
    const float* __restrict__ wq, const float* __restrict__ wk,
    const float* __restrict__ wv, const float* __restrict__ wm,
    u16* __restrict__ wqkv_p, u16* __restrict__ wm_p)
{
    const int t = threadIdx.x;
    const int c = t & 15, qn = t >> 4;
    const int quad = qn & 3, ntl = qn >> 2;   // ntl 0..3
    const int blk = blockIdx.x;
    if (blk < 32){
        const int s = blk >> 1, hh = blk & 1;
        const int krow = s*32 + quad*8;
        u16* dst = wqkv_p + (size_t)s*20480;
        #pragma unroll
        for (int i=0;i<5;++i){
            const int nt = hh*20 + i*4 + ntl;
            const int n = nt*16 + c;
            const float* src; int ldw;
            if (n < 64){ src = wq + (size_t)krow*64 + n; ldw = 64; }
            else if (n < 128){ src = wk + (size_t)krow*64 + (n-64); ldw = 64; }
            else { src = wv + (size_t)krow*512 + (n-128); ldw = 512; }
            float v[8];
            #pragma unroll
            for (int j=0;j<8;++j) v[j] = src[(size_t)j*ldw];
            uint4 o; o.x=pk2(v[0],v[1]); o.y=pk2(v[2],v[3]); o.z=pk2(v[4],v[5]); o.w=pk2(v[6],v[7]);
            *(uint4*)&dst[((nt*4+quad)*16 + c)*8] = o;
        }
    } else {
        const int bb = blk - 32;
        const int s = bb >> 1, hh = bb & 1;
        const int krow = s*32 + quad*8;
        u16* dst = wm_p + (size_t)s*16384;
        #pragma unroll
        for (int i=0;i<4;++i){
            const int nt = hh*16 + i*4 + ntl;
            const int n = nt*16 + c;
            const float* src = wm + (size_t)krow*512 + n;
            float v[8];
            #pragma unroll
            for (int j=0;j<8;++j) v[j] = src[(size_t)j*512];
            uint4 o; o.x=pk2(v[0],v[1]); o.y=pk2(v[2],v[3]); o.z=pk2(v[4],v[5]); o.w=pk2(v[6],v[7]);
            *(uint4*)&dst[((nt*4+quad)*16 + c)*8] = o;
        }
    }
}

// ---------------- K1: fused QKV projection, reg-direct B, no in-loop barriers --
// 256 blocks x 512 thr; 32 rows/block; 8 waves x 80 cols x 2 row-tiles.
__global__ __launch_bounds__(512) void k1_qkv(
    const float* __restrict__ x, const float* __restrict__ bq, const float* __restrict__ bk,
    const u16* __restrict__ wqkv_p,
    u16* __restrict__ Qb, u16* __restrict__ Kb, u16* __restrict__ Vb)
{
    __shared__ u16 Asf[16384];      // 32 KB: 2 rt x 16 s x 512 (A frags)
    const int t = threadIdx.x, w = t>>6, lane = t&63, quad = (lane>>4)&3, c = lane&15;
    const int rowbase = blockIdx.x << 5;

    // prefetch B s=0 (issued before A-stage so it overlaps)
    bh8 bw[5];
    #pragma unroll
    for (int nt2=0;nt2<5;++nt2)
        bw[nt2] = *(const bh8*)&wqkv_p[(size_t)((w*5+nt2)*4 + quad)*128 + c*8];
    // stage A (32 rows x 512 f32 -> bf16 frag order), coalesced float4
    #pragma unroll
    for (int i=0;i<8;++i){
        const int idx = t + (i<<9);            // 0..4095 float4 units
        const int fr = idx >> 7, fc4 = idx & 127;
        float4 xv = *(const float4*)&x[(size_t)(rowbase+fr)*512 + fc4*4];
        uint2 pkv; pkv.x = pk2(xv.x,xv.y); pkv.y = pk2(xv.z,xv.w);
        const int s = fc4 >> 3, qd = (fc4 >> 1) & 3, j0 = (fc4 & 1)*4;
        *(uint2*)&Asf[(fr>>4)*8192 + s*512 + (qd*16 + (fr&15))*8 + j0] = pkv;
    }
    f4 acc[2][5];
    #pragma unroll
    for (int rt=0;rt<2;++rt)
        #pragma unroll
        for (int i=0;i<5;++i) acc[rt][i] = (f4){0.f,0.f,0.f,0.f};
    __syncthreads();

    #pragma unroll
    for (int s=0;s<16;++s){
        bh8 bn[5];
        if (s+1 < 16){
            #pragma unroll
            for (int nt2=0;nt2<5;++nt2)
                bn[nt2] = *(const bh8*)&wqkv_p[(size_t)(s+1)*20480 + ((w*5+nt2)*4 + quad)*128 + c*8];
        }
        bh8 a[2];
        #pragma unroll
        for (int rt=0;rt<2;++rt)
            a[rt] = *(const bh8*)&Asf[rt*8192 + s*512 + (quad*16+c)*8];
        __builtin_amdgcn_s_setprio(1);
        #pragma unroll
        for (int rt=0;rt<2;++rt)
            #pragma unroll
            for (int nt2=0;nt2<5;++nt2)
                acc[rt][nt2] = MFMA16(a[rt], bw[nt2], acc[rt][nt2]);
        __builtin_amdgcn_s_setprio(0);
        if (s+1 < 16){
            #pragma unroll
            for (int nt2=0;nt2<5;++nt2) bw[nt2] = bn[nt2];
        }
    }

    // epilogue: Q/K -> frag panels (+bias); V -> B-operand frag layout (no bias)
    const int bd = rowbase >> 8;
    #pragma unroll
    for (int rt=0;rt<2;++rt){
        const int rtg = (blockIdx.x<<1) + rt;
        const int kloc = (rowbase & 255) + rt*16 + quad*4;     // + reg
        const int sv = kloc >> 5, kq = (kloc >> 3) & 3, jk0 = kloc & 7;
        #pragma unroll
        for (int nt2=0;nt2<5;++nt2){
            const int colb = w*80 + nt2*16;
            if (colb < 128){
                const bool isK = (colb >= 64);
                const int r = colb - (isK ? 64 : 0) + c;
                const float bias = isK ? bk[r] : bq[r];
                u16* dstb = (isK ? Kb : Qb) + ((size_t)(rtg*2 + (r>>5))*4 + ((r>>3)&3))*128 + (r&7);
                #pragma unroll
                for (int reg=0;reg<4;++reg)
                    dstb[(quad*4+reg)*8] = bf16r(acc[rt][nt2][reg] + bias);
            } else {
                const int ntv = (colb - 128) >> 4;             // channel group; col-in-tile = c
                u16* dstv = Vb + (size_t)bd*131072 + (size_t)sv*16384
                               + (size_t)((ntv*4+kq)*128 + c*8 + jk0);
                ushort4 o;
                o.x = bf16r(acc[rt][nt2][0]); o.y = bf16r(acc[rt][nt2][1]);
                o.z = bf16r(acc[rt][nt2][2]); o.w = bf16r(acc[rt][nt2][3]);
                *(ushort4*)dstv = o;
            }
        }
    }
}

// ---------------- K234: attn + LN + MLP + LN, reg-direct B, 5 barriers total --
// 256 blocks x 512 thr; 32 rows/block; 8 waves x 64 cols (32 keys-h) x 2 rt.
__global__ __launch_bounds__(512) void k234(
    const u16* __restrict__ Qb, const u16* __restrict__ Kb, const u16* __restrict__ Vb,
    const u16* __restrict__ wm_p,
    const float* __restrict__ x, const float* __restrict__ bv,
    const float* __restrict__ g1, const float* __restrict__ b1,
    const float* __restrict__ bm, const float* __restrict__ g2, const float* __restrict__ b2,
    float* __restrict__ out)
{
    __shared__ u16 U[16384];        // 32 KB union: a2f = U[0..8191] (2rt x 8s x 512)
                                    //              y1f = U[0..16383] (2rt x 16s x 512)
    __shared__ float redA[256], redB[256];   // [w(8)][rt(2)][q(16)]
    const int t = threadIdx.x, w = t>>6, lane = t&63, quad = (lane>>4)&3, c = lane&15;
    const int bd = blockIdx.x & 31, ftile = blockIdx.x >> 5;   // XCD-aligned decode
    const int b = bd >> 3;
    const int rowbase = (bd<<8) + (ftile<<5);
    const int rt00 = rowbase >> 4;
    const u16* Kp = Kb + (size_t)b*131072;
    const u16* Vp = Vb + (size_t)bd*131072;

    // ---- Q frags, reg-direct (broadcast across waves; 4 KB/wave)
    bh8 aq[2][2];
    #pragma unroll
    for (int rt=0;rt<2;++rt)
        #pragma unroll
        for (int kk=0;kk<2;++kk)
            aq[rt][kk] = *(const bh8*)&Qb[(size_t)(rt00+rt)*1024 + kk*512 + (quad*16+c)*8];

    float a2r[2][2][4] = {};
    // ---- Phase A: 8 depth-chunks x 256 keys; wave owns 32 h-cols (2 kt tiles)
    bh8 bk0[2][2];
    #pragma unroll
    for (int kt=0;kt<2;++kt)
        #pragma unroll
        for (int kk=0;kk<2;++kk)
            bk0[kt][kk] = *(const bh8*)&Kp[(size_t)(w*2+kt)*1024 + kk*512 + (quad*16+c)*8];
    #pragma unroll
    for (int cc=0; cc<8; ++cc){
        bh8 bn[2][2];
        if (cc+1 < 8){
            #pragma unroll
            for (int kt=0;kt<2;++kt)
                #pragma unroll
                for (int kk=0;kk<2;++kk)
                    bn[kt][kk] = *(const bh8*)&Kp[(size_t)((cc+1)*16 + w*2+kt)*1024 + kk*512 + (quad*16+c)*8];
        }
        f4 sa[2][2];
        __builtin_amdgcn_s_setprio(1);
        #pragma unroll
        for (int rt=0;rt<2;++rt)
            #pragma unroll
            for (int kt=0;kt<2;++kt){
                sa[rt][kt] = (f4){0.f,0.f,0.f,0.f};
                sa[rt][kt] = MFMA16(aq[rt][0], bk0[kt][0], sa[rt][kt]);
                sa[rt][kt] = MFMA16(aq[rt][1], bk0[kt][1], sa[rt][kt]);
            }
        __builtin_amdgcn_s_setprio(0);
        #pragma unroll
        for (int rt=0;rt<2;++rt)
            #pragma unroll
            for (int kt=0;kt<2;++kt)
                #pragma unroll
                for (int reg=0;reg<4;++reg)
                    a2r[rt][kt][reg] += __expf(sa[rt][kt][reg]);
        if (cc+1 < 8){
            #pragma unroll
            for (int kt=0;kt<2;++kt)
                #pragma unroll
                for (int kk=0;kk<2;++kk) bk0[kt][kk] = bn[kt][kk];
        }
    }
    // prefetch V s=0 (independent of softmax)
    bh8 bv8[4];
    #pragma unroll
    for (int nt2=0;nt2<4;++nt2)
        bv8[nt2] = *(const bh8*)&Vp[(size_t)((w*4+nt2)*4 + quad)*128 + c*8];
    // softmax denominator: lp = sum_kt a2r; shfl over c lanes, then across 8 waves
    float lp[2][4];
    #pragma unroll
    for (int rt=0;rt<2;++rt)
        #pragma unroll
        for (int reg=0;reg<4;++reg){
            float v = a2r[rt][0][reg] + a2r[rt][1][reg];
            v += __shfl_xor(v,1,64); v += __shfl_xor(v,2,64);
            v += __shfl_xor(v,4,64); v += __shfl_xor(v,8,64);
            lp[rt][reg] = v;
        }
    if (c==0){
        #pragma unroll
        for (int rt=0;rt<2;++rt)
            #pragma unroll
            for (int reg=0;reg<4;++reg) redA[w*32 + rt*16 + quad*4+reg] = lp[rt][reg];
    }
    LKBAR();
    float fac[2][4];
    #pragma unroll
    for (int rt=0;rt<2;++rt)
        #pragma unroll
        for (int reg=0;reg<4;++reg){
            const int q = rt*16 + quad*4 + reg;
            float s = 0.f;
            #pragma unroll
            for (int ww=0;ww<8;++ww) s += redA[ww*32 + q];
            fac[rt][reg] = 1.f/s;
        }
    #pragma unroll
    for (int rt=0;rt<2;++rt)
        #pragma unroll
        for (int kt=0;kt<2;++kt)
            #pragma unroll
            for (int reg=0;reg<4;++reg){
                const int jp = w*32 + kt*16 + c;
                U[rt*4096 + (jp>>5)*512 + (((jp>>3)&3)*16 + quad*4+reg)*8 + (jp&7)]
                    = bf16r(a2r[rt][kt][reg]*fac[rt][reg]);
            }
    LKBAR();                        // a2f visible; V prefetch (regs) untouched

    // ---- early-issue epilogue-1 operand loads (T14): x residual + bv/g1/b1
    //      column vectors; latency hides under phase B's MFMA steps.
    float xr[2][4][4];
    float bvr[4], g1r[4], b1r[4];
    #pragma unroll
    for (int nt2=0;nt2<4;++nt2){
        const int col = w*64 + nt2*16 + c;
        bvr[nt2] = bv[col]; g1r[nt2] = g1[col]; b1r[nt2] = b1[col];
        #pragma unroll
        for (int rt=0;rt<2;++rt)
            #pragma unroll
            for (int reg=0;reg<4;++reg){
                const int row = rowbase + rt*16 + quad*4 + reg;
                xr[rt][nt2][reg] = x[(size_t)row*512 + col];
            }
    }

    // ---- Phase B: attn = a2 @ V  (K=256, 8 steps, barrier-free)
    f4 cacc[2][4];
    #pragma unroll
    for (int rt=0;rt<2;++rt)
        #pragma unroll
        for (int i=0;i<4;++i) cacc[rt][i] = (f4){0.f,0.f,0.f,0.f};
    #pragma unroll
    for (int s8=0;s8<8;++s8){
        bh8 bn[4];
        if (s8+1 < 8){
            #pragma unroll
            for (int nt2=0;nt2<4;++nt2)
                bn[nt2] = *(const bh8*)&Vp[(size_t)(s8+1)*16384 + ((w*4+nt2)*4 + quad)*128 + c*8];
        }
        bh8 a[2];
        #pragma unroll
        for (int rt=0;rt<2;++rt)
            a[rt] = *(const bh8*)&U[rt*4096 + s8*512 + (quad*16+c)*8];
        __builtin_amdgcn_s_setprio(1);
        #pragma unroll
        for (int rt=0;rt<2;++rt)
            #pragma unroll
            for (int nt2=0;nt2<4;++nt2)
                cacc[rt][nt2] = MFMA16(a[rt], bv8[nt2], cacc[rt][nt2]);
        __builtin_amdgcn_s_setprio(0);
        if (s8+1 < 8){
            #pragma unroll
            for (int nt2=0;nt2<4;++nt2) bv8[nt2] = bn[nt2];
        }
    }
    // prefetch wm s=0 (latency covered by epilogue 1)
    bh8 bm8[4];
    #pragma unroll
    for (int nt2=0;nt2<4;++nt2)
        bm8[nt2] = *(const bh8*)&wm_p[(size_t)((w*4+nt2)*4 + quad)*128 + c*8];

    // ---- epilogue 1: + bv + x residual, LN -> y1 (f32 in cacc, bf16 frags in y1f)
    float mean1[2][4], rstd1[2][4];
    {
        float sv4[2][4] = {}, qv2[2][4] = {};
        #pragma unroll
        for (int rt=0;rt<2;++rt)
            #pragma unroll
            for (int nt2=0;nt2<4;++nt2){
                #pragma unroll
                for (int reg=0;reg<4;++reg){
                    float val = cacc[rt][nt2][reg] + bvr[nt2] + xr[rt][nt2][reg];
                    cacc[rt][nt2][reg] = val;
                    sv4[rt][reg] += val; qv2[rt][reg] = fmaf(val,val,qv2[rt][reg]);
                }
            }
        #pragma unroll
        for (int rt=0;rt<2;++rt)
            #pragma unroll
            for (int reg=0;reg<4;++reg){
                float s1=sv4[rt][reg], s2=qv2[rt][reg];
                s1 += __shfl_xor(s1,1,64); s2 += __shfl_xor(s2,1,64);
                s1 += __shfl_xor(s1,2,64); s2 += __shfl_xor(s2,2,64);
                s1 += __shfl_xor(s1,4,64); s2 += __shfl_xor(s2,4,64);
                s1 += __shfl_xor(s1,8,64); s2 += __shfl_xor(s2,8,64);
                sv4[rt][reg]=s1; qv2[rt][reg]=s2;
            }
        if (c==0){
            #pragma unroll
            for (int rt=0;rt<2;++rt)
                #pragma unroll
                for (int reg=0;reg<4;++reg){
                    redA[w*32 + rt*16 + quad*4+reg]=sv4[rt][reg];
                    redB[w*32 + rt*16 + quad*4+reg]=qv2[rt][reg];
                }
        }
        LKBAR();                    // all waves past phase B -> a2f dead, y1f may alias
        #pragma unroll
        for (int rt=0;rt<2;++rt)
            #pragma unroll
            for (int reg=0;reg<4;++reg){
                const int q = rt*16 + quad*4 + reg;
                float S=0.f, Q2=0.f;
                #pragma unroll
                for (int ww=0;ww<8;++ww){ S += redA[ww*32+q]; Q2 += redB[ww*32+q]; }
                const float m = S*(1.f/512.f);
                mean1[rt][reg]=m; rstd1[rt][reg]=rsqrtf(Q2*(1.f/512.f) - m*m + LN_EPS);
            }
        #pragma unroll
        for (int rt=0;rt<2;++rt)
            #pragma unroll
            for (int nt2=0;nt2<4;++nt2){
                const int col = w*64 + nt2*16 + c;
                #pragma unroll
                for (int reg=0;reg<4;++reg){
                    float y = (cacc[rt][nt2][reg]-mean1[rt][reg])*rstd1[rt][reg]*g1r[nt2] + b1r[nt2];
                    cacc[rt][nt2][reg] = y;
                    U[rt*8192 + (col>>5)*512 + (((col>>3)&3)*16 + quad*4+reg)*8 + (col&7)] = bf16r(y);
                }
            }
        LKBAR();                    // y1f visible; wm prefetch (regs) untouched
    }

    // ---- Phase D: mlp = y1 @ wm (K=512, 16 steps, barrier-free)
    f4 dacc[2][4];
    #pragma unroll
    for (int rt=0;rt<2;++rt)
        #pragma unroll
        for (int i=0;i<4;++i) dacc[rt][i] = (f4){0.f,0.f,0.f,0.f};
    #pragma unroll
    for (int s=0;s<16;++s){
        bh8 bn[4];
        if (s+1 < 16){
            #pragma unroll
            for (int nt2=0;nt2<4;++nt2)
                bn[nt2] = *(const bh8*)&wm_p[(size_t)(s+1)*16384 + ((w*4+nt2)*4 + quad)*128 + c*8];
        }
        bh8 a[2];
        #pragma unroll
        for (int rt=0;rt<2;++rt)
            a[rt] = *(const bh8*)&U[rt*8192 + s*512 + (quad*16+c)*8];
        __builtin_amdgcn_s_setprio(1);
        #pragma unroll
        for (int rt=0;rt<2;++rt)
            #pragma unroll
            for (int nt2=0;nt2<4;++nt2)
                dacc[rt][nt2] = MFMA16(a[rt], bm8[nt2], dacc[rt][nt2]);
        __builtin_amdgcn_s_setprio(0);
        if (s+1 < 16){
            #pragma unroll
            for (int nt2=0;nt2<4;++nt2) bm8[nt2] = bn[nt2];
        }
    }

    // ---- epilogue 2: relu(+bm) + y1 residual, LN -> out
    {
        float sv4[2][4] = {}, qv2[2][4] = {};
        #pragma unroll
        for (int rt=0;rt<2;++rt)
            #pragma unroll
            for (int nt2=0;nt2<4;++nt2){
                const int col = w*64 + nt2*16 + c;
                const float bmv = bm[col];
                #pragma unroll
                for (int reg=0;reg<4;++reg){
                    float hh = fmaxf(dacc[rt][nt2][reg]+bmv, 0.f) + cacc[rt][nt2][reg];
                    dacc[rt][nt2][reg] = hh;
                    sv4[rt][reg] += hh; qv2[rt][reg] = fmaf(hh,hh,qv2[rt][reg]);
                }
            }
        #pragma unroll
        for (int rt=0;rt<2;++rt)
            #pragma unroll
            for (int reg=0;reg<4;++reg){
                float s1=sv4[rt][reg], s2=qv2[rt][reg];
                s1 += __shfl_xor(s1,1,64); s2 += __shfl_xor(s2,1,64);
                s1 += __shfl_xor(s1,2,64); s2 += __shfl_xor(s2,2,64);
                s1 += __shfl_xor(s1,4,64); s2 += __shfl_xor(s2,4,64);
                s1 += __shfl_xor(s1,8,64); s2 += __shfl_xor(s2,8,64);
                sv4[rt][reg]=s1; qv2[rt][reg]=s2;
            }
        if (c==0){
            #pragma unroll
            for (int rt=0;rt<2;++rt)
                #pragma unroll
                for (int reg=0;reg<4;++reg){
                    redA[w*32 + rt*16 + quad*4+reg]=sv4[rt][reg];
                    redB[w*32 + rt*16 + quad*4+reg]=qv2[rt][reg];
                }
        }
        LKBAR();
        #pragma unroll
        for (int rt=0;rt<2;++rt){
            float mean[4], rstd[4];
            #pragma unroll
            for (int reg=0;reg<4;++reg){
                const int q = rt*16 + quad*4 + reg;
                float S=0.f, Q2=0.f;
                #pragma unroll
                for (int ww=0;ww<8;++ww){ S += redA[ww*32+q]; Q2 += redB[ww*32+q]; }
                const float m = S*(1.f/512.f);
                mean[reg]=m; rstd[reg]=rsqrtf(Q2*(1.f/512.f) - m*m + LN_EPS);
            }
            #pragma unroll
            for (int nt2=0;nt2<4;++nt2){
                const int col = w*64 + nt2*16 + c;
                const float gg = g2[col], bb2 = b2[col];
                #pragma unroll
                for (int reg=0;reg<4;++reg){
                    const int row = rowbase + rt*16 + quad*4 + reg;
                    out[(size_t)row*512 + col] = (dacc[rt][nt2][reg]-mean[reg])*rstd[reg]*gg + bb2;
                }
            }
        }
    }
}

extern "C" void kernel_launch(void* const* d_in, const int* in_sizes, int n_in,
                              void* d_out, int out_size, void* d_ws, size_t ws_size,
                              hipStream_t stream) {
    (void)in_sizes; (void)n_in; (void)out_size; (void)ws_size;
    const float* x  = (const float*)d_in[0];
    const float* wq = (const float*)d_in[1];
    const float* bq = (const float*)d_in[2];
    const float* wk = (const float*)d_in[3];
    const float* bk = (const float*)d_in[4];
    const float* wv = (const float*)d_in[5];
    const float* bv = (const float*)d_in[6];
    const float* wm = (const float*)d_in[7];
    const float* bm = (const float*)d_in[8];
    const float* g1 = (const float*)d_in[9];
    const float* b1 = (const float*)d_in[10];
    const float* g2 = (const float*)d_in[11];
    const float* b2 = (const float*)d_in[12];

    // ws layout (11.67 MB): bf16 frag panels
    u16* wqkv_p = (u16*)d_ws;                  // 640 KB (16 s x 40 nt x 512)
    u16* wm_p   = wqkv_p + 327680;             // 512 KB
    u16* Qb     = wm_p   + 262144;             // 1 MB  (512 rt x 2048 B)
    u16* Kb     = Qb     + 524288;             // 1 MB
    u16* Vb     = Kb     + 524288;             // 8 MB  (32 bd x 8 s x 16384 u16)
    float* outp = (float*)d_out;

    k0_prep<<<64, 256, 0, stream>>>(wq, wk, wv, wm, wqkv_p, wm_p);
    k1_qkv <<<256, 512, 0, stream>>>(x, bq, bk, wqkv_p, Qb, Kb, Vb);
    k234   <<<256, 512, 0, stream>>>(Qb, Kb, Vb, wm_p, x, bv, g1, b1, bm, g2, b2, outp);
}